// Round 6
// baseline (80.958 us; speedup 1.0000x reference)
//
#include <hip/hip_runtime.h>

#define N_ROWS 2048
#define L 128
#define FGV 2.0f
#define CROWS 8    // rows of n staged per block -> 768 blocks = 3/CU exactly

// ws layout: partials[0..767]    = per-block loss partials (tile*256+bx)
//            partials[768..1023] = per-(tile0-block) sum(f) partials
//            counter at float-offset 1024 (unsigned)
#define NBLOCKS 768u
#define POISON_BASE 0xAAAAAAAAu

__device__ __forceinline__ float waveReduceSum(float v) {
#pragma unroll
    for (int off = 32; off > 0; off >>= 1)
        v += __shfl_down(v, off, 64);
    return v;
}

// ---------------------------------------------------------------------------
// Single-dispatch fused kernel: grid (256 n-chunks, 3 (i,j) tiles).
//   tile 0: i in [0,64),  j in [0,64)    -- also computes sum(f) + k==0 terms
//   tile 1: i in [0,64),  j in [64,128)
//   tile 2: i in [64,128),j in [64,128)
// Stage (d,f) for CROWS rows to LDS, register-tile 4x4 pairs/thread,
// accumulate S1=sum(a*fi*fj), S2=sum(a^2*fi*fj) over n in registers, apply
// n-independent weights in the epilogue (k<1 skipped => auto-zero; scattered
// w loads are L1/L2-resident — R5 proved coalescing them is a net loss),
// block reduce -> own ws slot. Then last-block finalize:
//   release fence -> atomicAdd(counter); the block whose old value is
//   767 (zero-init) or 0xAAAAAAAA+767 (0xAA poison) -- disjoint ranges, so
//   exactly one winner under either init -- acquire-fences and reduces the
//   1024 partials to out[0] = loss/sumf.
// NOTE: cooperative launch silently fails under this harness (R4).
// ---------------------------------------------------------------------------
__global__ __launch_bounds__(256)
void fused_kernel(const float* __restrict__ yt, const float* __restrict__ yp,
                  const float* __restrict__ yd, const float* __restrict__ w,
                  float* __restrict__ partials, unsigned* __restrict__ counter,
                  float* __restrict__ out) {
    const int tile = blockIdx.y;
    const int i0 = (tile == 2) ? 64 : 0;
    const int j0 = (tile == 0) ? 0 : 64;
    const int tid = threadIdx.x;

    __shared__ float2 sh[CROWS][L];   // (d, f) per element, 8 KB

    float sumf = 0.f;   // only tile 0 accumulates
    float diag = 0.f;   // k==0 loss terms, only tile 0
    {
        // CROWS*L = 1024 elements, exactly one float4 per thread per array.
        int base = blockIdx.x * (CROWS * L) + tid * 4;
        float4 aa = *(const float4*)(yt + base);
        float4 bb = *(const float4*)(yp + base);
        float4 cc = *(const float4*)(yd + base);
        float d[4] = {aa.x - bb.x, aa.y - bb.y, aa.z - bb.z, aa.w - bb.w};
        float f[4] = {fabsf(cc.x) <= FGV ? 1.f : 0.f,
                      fabsf(cc.y) <= FGV ? 1.f : 0.f,
                      fabsf(cc.z) <= FGV ? 1.f : 0.f,
                      fabsf(cc.w) <= FGV ? 1.f : 0.f};
        float2* o = &sh[0][0] + tid * 4;
#pragma unroll
        for (int e = 0; e < 4; e++) {
            o[e] = make_float2(d[e], f[e]);
            if (tile == 0) {   // block-uniform branch, no divergence
                int i = (tid * 4 + e) & (L - 1);
                float ad = fabsf(d[e]);
                sumf += f[e];
                // weights[0][i][0] and weights[1][i][0]
                diag += f[e] * fmaf(w[L * L + i * L], ad * ad, w[i * L] * ad);
            }
        }
    }
    __syncthreads();

    const int tx = tid & 15;   // i fragment (strided by 16 -> conflict-free)
    const int ty = tid >> 4;   // j fragment (contiguous by 4 -> b128 broadcast)

    float s1[4][4] = {{0.f}};
    float s2[4][4] = {{0.f}};

#pragma unroll 2
    for (int n = 0; n < CROWS; n++) {
        float2 vi[4], vj[4];
#pragma unroll
        for (int aq = 0; aq < 4; aq++) vi[aq] = sh[n][i0 + tx + 16 * aq];
#pragma unroll
        for (int bq = 0; bq < 4; bq++) vj[bq] = sh[n][j0 + ty * 4 + bq];
        float ej[4];
#pragma unroll
        for (int bq = 0; bq < 4; bq++) ej[bq] = vj[bq].x * vj[bq].y;  // d_j*f_j
#pragma unroll
        for (int aq = 0; aq < 4; aq++) {
#pragma unroll
            for (int bq = 0; bq < 4; bq++) {
                // t0 = |d_i - d_j| * f_j  (f_j in {0,1} so abs(fma) works)
                float t0 = fabsf(fmaf(vi[aq].x, vj[bq].y, -ej[bq]));
                float t1 = t0 * vi[aq].y;               // * f_i
                s1[aq][bq] += t1;                       // a   * fi*fj
                s2[aq][bq] = fmaf(t0, t1, s2[aq][bq]);  // a^2 * fi*fj
            }
        }
    }

    // Epilogue: apply n-independent weights; k<1 skipped (auto-zero).
    float total = diag;
#pragma unroll
    for (int aq = 0; aq < 4; aq++) {
        int i = i0 + tx + 16 * aq;
#pragma unroll
        for (int bq = 0; bq < 4; bq++) {
            int j = j0 + ty * 4 + bq;
            int k = j - i;
            if (k >= 1) {
                total = fmaf(s1[aq][bq], w[i * L + k], total);
                total = fmaf(s2[aq][bq], w[L * L + i * L + k], total);
            }
        }
    }

    // Block-reduce (loss, sumf) and write this block's ws slots.
    __shared__ float redL[4], redF[4];
    __shared__ unsigned sLast;
    float sL = waveReduceSum(total);
    float sF = waveReduceSum(sumf);
    int wave = tid >> 6, lane = tid & 63;
    if (lane == 0) { redL[wave] = sL; redF[wave] = sF; }
    __syncthreads();
    if (tid == 0) {
        partials[tile * 256 + blockIdx.x] = redL[0] + redL[1] + redL[2] + redL[3];
        if (tile == 0)
            partials[NBLOCKS + blockIdx.x] = redF[0] + redF[1] + redF[2] + redF[3];
        __threadfence();   // release: partials visible before counter bump
        unsigned old = atomicAdd(counter, 1u);
        sLast = (old == NBLOCKS - 1u) || (old == POISON_BASE + NBLOCKS - 1u);
    }
    __syncthreads();

    if (sLast) {           // block-uniform: exactly one block enters
        __threadfence();   // acquire: see all other blocks' partials
        // 1024 floats = 256 float4s, one per thread.
        // float4 idx 0..191 -> loss slots, 192..255 -> sumf slots.
        const float4* p4 = (const float4*)partials;
        float4 v = p4[tid];
        float s = (v.x + v.y) + (v.z + v.w);
        float lossAcc = (tid < 192) ? s : 0.f;
        float fAcc    = (tid < 192) ? 0.f : s;
        float rL = waveReduceSum(lossAcc);
        float rF = waveReduceSum(fAcc);
        if (lane == 0) { redL[wave] = rL; redF[wave] = rF; }
        __syncthreads();
        if (tid == 0)
            out[0] = (redL[0] + redL[1] + redL[2] + redL[3]) /
                     (redF[0] + redF[1] + redF[2] + redF[3]);
    }
}

extern "C" void kernel_launch(void* const* d_in, const int* in_sizes, int n_in,
                              void* d_out, int out_size, void* d_ws, size_t ws_size,
                              hipStream_t stream) {
    const float* yt = (const float*)d_in[0];
    const float* yp = (const float*)d_in[1];
    const float* yd = (const float*)d_in[2];
    const float* w  = (const float*)d_in[3];
    float* partials = (float*)d_ws;                    // 1024 floats
    unsigned* counter = (unsigned*)(partials + 1024);  // 1 uint, any-init safe
    float* out = (float*)d_out;

    fused_kernel<<<dim3(N_ROWS / CROWS, 3), 256, 0, stream>>>(
        yt, yp, yd, w, partials, counter, out);
}

// Round 7
// 67.724 us; speedup vs baseline: 1.1954x; 1.1954x over previous
//
#include <hip/hip_runtime.h>

#define N_ROWS 2048
#define L 128
#define FGV 2.0f
#define CROWS 8    // rows of n staged per block -> 768 blocks = 3/CU exactly

// ws layout: partials[0..767]    = per-block loss partials (tile*256+bx)
//            partials[768..1023] = per-(tile0-block) sum(f) partials
#define NLOSS 768
#define NTOT  1024

// Session findings (measured):
//  R4: hipLaunchCooperativeKernel silently no-ops under this harness -> fail.
//  R5: LDS-transposing the epilogue to coalesce w-loads REGRESSED (+2.5us):
//      w is 128KB, L1/L2-resident; coalescing only pays on HBM streams.
//  R6: single-dispatch last-block finalize REGRESSED (+13.3us): device-scope
//      __threadfence + single-line atomic across 8 XCDs >> one extra dispatch.
//  => this two-dispatch structure at 67.7us sits ~6us above the harness floor
//     (40.5us ws-poison fill + input restores + graph gaps ~= 60-62us).

__device__ __forceinline__ float waveReduceSum(float v) {
#pragma unroll
    for (int off = 32; off > 0; off >>= 1)
        v += __shfl_down(v, off, 64);
    return v;
}

// ---------------------------------------------------------------------------
// Fused kernel: grid (256 n-chunks, 3 (i,j) tiles).
//   tile 0: i in [0,64),  j in [0,64)    -- also computes sum(f) + k==0 terms
//   tile 1: i in [0,64),  j in [64,128)
//   tile 2: i in [64,128),j in [64,128)
// Stage (d,f) for CROWS rows to LDS, register-tile 4x4 pairs/thread,
// accumulate S1=sum(a*fi*fj), S2=sum(a^2*fi*fj) over n in registers, apply
// n-independent weights in the epilogue (k<1 skipped => auto-zero), block
// reduce, write partial to this block's own ws slot (no zero-init/atomics).
// ---------------------------------------------------------------------------
__global__ __launch_bounds__(256)
void fused_kernel(const float* __restrict__ yt, const float* __restrict__ yp,
                  const float* __restrict__ yd, const float* __restrict__ w,
                  float* __restrict__ partials) {
    const int tile = blockIdx.y;
    const int i0 = (tile == 2) ? 64 : 0;
    const int j0 = (tile == 0) ? 0 : 64;
    const int tid = threadIdx.x;

    __shared__ float2 sh[CROWS][L];   // (d, f) per element, 8 KB

    float sumf = 0.f;   // only tile 0 accumulates
    float diag = 0.f;   // k==0 loss terms, only tile 0
    {
        // CROWS*L = 1024 elements, exactly one float4 per thread per array.
        int base = blockIdx.x * (CROWS * L) + tid * 4;
        float4 aa = *(const float4*)(yt + base);
        float4 bb = *(const float4*)(yp + base);
        float4 cc = *(const float4*)(yd + base);
        float d[4] = {aa.x - bb.x, aa.y - bb.y, aa.z - bb.z, aa.w - bb.w};
        float f[4] = {fabsf(cc.x) <= FGV ? 1.f : 0.f,
                      fabsf(cc.y) <= FGV ? 1.f : 0.f,
                      fabsf(cc.z) <= FGV ? 1.f : 0.f,
                      fabsf(cc.w) <= FGV ? 1.f : 0.f};
        float2* o = &sh[0][0] + tid * 4;
#pragma unroll
        for (int e = 0; e < 4; e++) {
            o[e] = make_float2(d[e], f[e]);
            if (tile == 0) {   // block-uniform branch, no divergence
                int i = (tid * 4 + e) & (L - 1);
                float ad = fabsf(d[e]);
                sumf += f[e];
                // weights[0][i][0] and weights[1][i][0]
                diag += f[e] * fmaf(w[L * L + i * L], ad * ad, w[i * L] * ad);
            }
        }
    }
    __syncthreads();

    const int tx = tid & 15;   // i fragment (strided by 16 -> conflict-free)
    const int ty = tid >> 4;   // j fragment (contiguous by 4 -> b128 broadcast)

    float s1[4][4] = {{0.f}};
    float s2[4][4] = {{0.f}};

#pragma unroll 2
    for (int n = 0; n < CROWS; n++) {
        float2 vi[4], vj[4];
#pragma unroll
        for (int aq = 0; aq < 4; aq++) vi[aq] = sh[n][i0 + tx + 16 * aq];
#pragma unroll
        for (int bq = 0; bq < 4; bq++) vj[bq] = sh[n][j0 + ty * 4 + bq];
        float ej[4];
#pragma unroll
        for (int bq = 0; bq < 4; bq++) ej[bq] = vj[bq].x * vj[bq].y;  // d_j*f_j
#pragma unroll
        for (int aq = 0; aq < 4; aq++) {
#pragma unroll
            for (int bq = 0; bq < 4; bq++) {
                // t0 = |d_i - d_j| * f_j  (f_j in {0,1} so abs(fma) works)
                float t0 = fabsf(fmaf(vi[aq].x, vj[bq].y, -ej[bq]));
                float t1 = t0 * vi[aq].y;               // * f_i
                s1[aq][bq] += t1;                       // a   * fi*fj
                s2[aq][bq] = fmaf(t0, t1, s2[aq][bq]);  // a^2 * fi*fj
            }
        }
    }

    // Epilogue: apply n-independent weights; k<1 skipped (auto-zero).
    // Scattered w loads are L1/L2-resident (128 KB table) -- cheap (R5).
    float total = diag;
#pragma unroll
    for (int aq = 0; aq < 4; aq++) {
        int i = i0 + tx + 16 * aq;
#pragma unroll
        for (int bq = 0; bq < 4; bq++) {
            int j = j0 + ty * 4 + bq;
            int k = j - i;
            if (k >= 1) {
                total = fmaf(s1[aq][bq], w[i * L + k], total);
                total = fmaf(s2[aq][bq], w[L * L + i * L + k], total);
            }
        }
    }

    // Block-reduce (loss, sumf) and write this block's ws slots.
    __shared__ float redL[4], redF[4];
    float sL = waveReduceSum(total);
    float sF = waveReduceSum(sumf);
    int wave = tid >> 6, lane = tid & 63;
    if (lane == 0) { redL[wave] = sL; redF[wave] = sF; }
    __syncthreads();
    if (tid == 0) {
        partials[tile * 256 + blockIdx.x] = redL[0] + redL[1] + redL[2] + redL[3];
        if (tile == 0)
            partials[NLOSS + blockIdx.x] = redF[0] + redF[1] + redF[2] + redF[3];
    }
}

// ---------------------------------------------------------------------------
// Final reduction: one wave, float4 loads. 1024 floats = 256 float4s.
// float4 idx t, t+64, t+128 -> loss; idx t+192 -> sumf.
// ---------------------------------------------------------------------------
__global__ __launch_bounds__(64)
void fin_kernel(const float* __restrict__ partials, float* __restrict__ out) {
    int t = threadIdx.x;
    const float4* p4 = (const float4*)partials;
    float lossAcc = 0.f, fAcc = 0.f;
#pragma unroll
    for (int q = 0; q < 3; q++) {
        float4 v = p4[t + q * 64];
        lossAcc += (v.x + v.y) + (v.z + v.w);
    }
    {
        float4 v = p4[t + 192];
        fAcc = (v.x + v.y) + (v.z + v.w);
    }
    float sL = waveReduceSum(lossAcc);
    float sF = waveReduceSum(fAcc);
    if (t == 0) out[0] = sL / sF;
}

extern "C" void kernel_launch(void* const* d_in, const int* in_sizes, int n_in,
                              void* d_out, int out_size, void* d_ws, size_t ws_size,
                              hipStream_t stream) {
    const float* yt = (const float*)d_in[0];
    const float* yp = (const float*)d_in[1];
    const float* yd = (const float*)d_in[2];
    const float* w  = (const float*)d_in[3];
    float* partials = (float*)d_ws;   // 1024 floats, all written every call
    float* out = (float*)d_out;

    fused_kernel<<<dim3(N_ROWS / CROWS, 3), 256, 0, stream>>>(yt, yp, yd, w, partials);
    fin_kernel<<<1, 64, 0, stream>>>(partials, out);
}